// Round 20
// baseline (913.141 us; speedup 1.0000x reference)
//
#include <hip/hip_runtime.h>
#include <hip/hip_bf16.h>

typedef __attribute__((ext_vector_type(8))) short bf16x8;
typedef __attribute__((ext_vector_type(4))) float f32x4;

static __device__ __forceinline__ void stf(float* p, size_t i, float v) { p[i] = v; }
static __device__ __forceinline__ void stf(__hip_bfloat16* p, size_t i, float v) { p[i] = __float2bfloat16(v); }

static __device__ __forceinline__ void gload_lds16(const void* g, void* l) {
  __builtin_amdgcn_global_load_lds((const __attribute__((address_space(1))) void*)g,
                                   (__attribute__((address_space(3))) void*)l, 16, 0, 0);
}

// ---------- weight transpose + bf16 convert: W[K][N] f32 -> WT[N][K] bf16 ----------
__global__ void wt_kernel(const float* __restrict__ W, __hip_bfloat16* __restrict__ WT, int K, int N) {
  __shared__ float tile[32][33];
  const int kb = blockIdx.y * 32, nb = blockIdx.x * 32;
  const int tx = threadIdx.x & 31, ty = threadIdx.x >> 5;
#pragma unroll
  for (int i = 0; i < 4; ++i)
    tile[ty + i * 8][tx] = W[(size_t)(kb + ty + i * 8) * N + nb + tx];
  __syncthreads();
#pragma unroll
  for (int i = 0; i < 4; ++i)
    WT[(size_t)(nb + ty + i * 8) * K + kb + tx] = __float2bfloat16(tile[tx][ty + i * 8]);
}

// ---------- conv prep ----------
__global__ void convprep_kernel(const float* __restrict__ w, const float* __restrict__ bng,
                                const float* __restrict__ bnb, const float* __restrict__ bnm,
                                const float* __restrict__ bnv, float* __restrict__ wT,
                                float* __restrict__ st) {
  const int i = blockIdx.x * 256 + threadIdx.x;
  if (i < 576 * 9) {
    const int t = i / 576, c = i - t * 576;
    wT[i] = w[c * 9 + t];
  }
  if (i < 576) {
    const float s = rsqrtf(bnv[i] + 1e-5f) * bng[i];
    st[i] = s;
    st[576 + i] = bnb[i] - bnm[i] * s;
  }
}

// ---------- fused LN -> bf16 ----------
__global__ void ln_bf16_kernel(const float* __restrict__ x, const float* __restrict__ g,
                               const float* __restrict__ b, __hip_bfloat16* __restrict__ y) {
  const int row = blockIdx.x * 4 + (threadIdx.x >> 6);
  const int lane = threadIdx.x & 63;
  const float* p = x + (size_t)row * 576;
  float vals[9];
  float s = 0.f, ss = 0.f;
#pragma unroll
  for (int i = 0; i < 9; ++i) {
    float v = p[lane + i * 64];
    vals[i] = v; s += v; ss += v * v;
  }
#pragma unroll
  for (int o = 32; o; o >>= 1) { s += __shfl_down(s, o); ss += __shfl_down(ss, o); }
  s = __shfl(s, 0); ss = __shfl(ss, 0);
  const float m = s * (1.f / 576.f);
  const float rstd = rsqrtf(ss * (1.f / 576.f) - m * m + 1e-5f);
  __hip_bfloat16* q = y + (size_t)row * 576;
#pragma unroll
  for (int i = 0; i < 9; ++i) {
    const int c = lane + i * 64;
    q[c] = __float2bfloat16((vals[i] - m) * rstd * g[c] + b[c]);
  }
}

// ---------- MFMA GEMM (R16 structure, BN templated): 128xBN, BK=32 ----------
// BN=64: 24KB LDS, 6 blk/CU (R16-exact, proven).  BN=192: 40KB LDS, 4 blk/CU,
// intensity 43 -> 79 F/staged-byte (24 MFMA per 20KB staged vs 8 per 12KB).
// Swizzle f(row)=(row>>1)&3 both-sides (conflicts 0). 2-phase __syncthreads
// loop, ascending-K accumulation (bit-identical across BN).
// EPI: 0 none, 1 +res, 2 exact GELU
template <int BN, int EPI, typename TO>
__global__ __launch_bounds__(256, (BN == 64 ? 6 : 4)) void gemm_bt(
    const __hip_bfloat16* __restrict__ A, const __hip_bfloat16* __restrict__ BT,
    const float* __restrict__ bias, const float* __restrict__ res, TO* __restrict__ C,
    int M, int N, int K) {
  constexpr int NI = BN / 32;        // 16-col frags per wave (wave tile 64 x BN/2)
  constexpr int BI = BN / 64;        // B stage iterations (256 thr, 16B each)
  __shared__ __hip_bfloat16 sA[2][128 * 32];
  __shared__ __hip_bfloat16 sB[2][BN * 32];
  const int t = threadIdx.x;
  const int lane = t & 63;
  const int w = t >> 6;
  const int nwg = gridDim.x;
  const int qq = nwg >> 3, r = nwg & 7;
  const int xcd = blockIdx.x & 7, lidx = blockIdx.x >> 3;
  const int wgid = (xcd < r ? xcd * (qq + 1) : r * (qq + 1) + (xcd - r) * qq) + lidx;
  const int nx = N / BN;
  const int bm = (wgid / nx) * 128, bn = (wgid % nx) * BN;
  const int wm = (w >> 1) * 64, wn = (w & 1) * (BN / 2);
  const int l15 = lane & 15, l4 = lane >> 4;
  const int wave_base = t & ~63;

  f32x4 acc[4][NI];
#pragma unroll
  for (int mi = 0; mi < 4; ++mi)
#pragma unroll
    for (int ni = 0; ni < NI; ++ni) acc[mi][ni] = (f32x4){0.f, 0.f, 0.f, 0.f};

  auto stage = [&](int buf, int k0) {
#pragma unroll
    for (int i = 0; i < 2; ++i) {
      const int slot = i * 256 + t;
      const int row = slot >> 2, kst = slot & 3;
      const int ksrc = kst ^ ((row >> 1) & 3);
      gload_lds16(A + (size_t)(bm + row) * K + k0 + ksrc * 8,
                  sA[buf] + (i * 256 + wave_base) * 8);
    }
#pragma unroll
    for (int i = 0; i < BI; ++i) {
      const int slot = i * 256 + t;
      const int row = slot >> 2, kst = slot & 3;
      const int ksrc = kst ^ ((row >> 1) & 3);
      gload_lds16(BT + (size_t)(bn + row) * K + k0 + ksrc * 8,
                  sB[buf] + (i * 256 + wave_base) * 8);
    }
  };

  auto compute = [&](int buf) {
    bf16x8 a[4], b[NI];
#pragma unroll
    for (int mi = 0; mi < 4; ++mi) {
      const int row = wm + mi * 16 + l15;
      a[mi] = *(const bf16x8*)(&sA[buf][row * 32 + ((l4 ^ ((row >> 1) & 3)) * 8)]);
    }
#pragma unroll
    for (int ni = 0; ni < NI; ++ni) {
      const int row = wn + ni * 16 + l15;
      b[ni] = *(const bf16x8*)(&sB[buf][row * 32 + ((l4 ^ ((row >> 1) & 3)) * 8)]);
    }
#pragma unroll
    for (int mi = 0; mi < 4; ++mi)
#pragma unroll
      for (int ni = 0; ni < NI; ++ni)
        acc[mi][ni] = __builtin_amdgcn_mfma_f32_16x16x32_bf16(a[mi], b[ni], acc[mi][ni], 0, 0, 0);
  };

  const int nt = K >> 5;
  stage(0, 0);
  __syncthreads();
  int cur = 0;
  for (int tt = 0; tt < nt - 1; ++tt) {
    stage(cur ^ 1, (tt + 1) << 5);
    compute(cur);
    __syncthreads();
    cur ^= 1;
  }
  compute(cur);

#pragma unroll
  for (int mi = 0; mi < 4; ++mi) {
    const int mrow = bm + wm + mi * 16 + l4 * 4;
#pragma unroll
    for (int ni = 0; ni < NI; ++ni) {
      const int col = bn + wn + ni * 16 + l15;
      const float bv = bias[col];
#pragma unroll
      for (int r2 = 0; r2 < 4; ++r2) {
        const size_t idx = (size_t)(mrow + r2) * N + col;
        float v = acc[mi][ni][r2] + bv;
        if (EPI == 1) v += res[idx];
        if (EPI == 2) v = 0.5f * v * (1.0f + erff(v * 0.70710678118654752f));
        stf(C, idx, v);
      }
    }
  }
}

// ---------- MFMA windowed attention, low-LDS (R12 config, kept) ----------
__global__ __launch_bounds__(64) void attn_mfma_kernel(
    const __hip_bfloat16* __restrict__ qkv, const float* __restrict__ biases,
    __hip_bfloat16* __restrict__ o) {
  __shared__ __hip_bfloat16 sVT[32][72];
  __shared__ __hip_bfloat16 sP[64][72];

  const int wid  = blockIdx.x / 18;
  const int head = blockIdx.x - wid * 18;
  const int b  = wid >> 4;
  const int wi = wid & 15;
  const int wh = wi >> 2, wwc = wi & 3;
  const int lane = threadIdx.x;
  const int l15 = lane & 15, l4 = lane >> 4;

  auto growof = [&](int tkn) -> size_t {
    const int r = tkn / 7, c = tkn - r * 7;
    return (size_t)b * 784 + (size_t)((wh * 7 + r) * 28 + wwc * 7 + c);
  };

  for (int idx = lane; idx < 49 * 4; idx += 64) {
    const int tkn = idx >> 2, part = idx & 3;
    const bf16x8 v = *(const bf16x8*)(qkv + growof(tkn) * 1728 + head * 96 + 64 + part * 8);
    const short* sv = (const short*)&v;
#pragma unroll
    for (int e = 0; e < 8; ++e)
      sVT[part * 8 + e][tkn] = *(const __hip_bfloat16*)&sv[e];
  }
  for (int idx = lane; idx < 32 * 15; idx += 64) {
    const int d = idx / 15, tt = 49 + (idx - d * 15);
    sVT[d][tt] = __float2bfloat16(0.0f);
  }

  bf16x8 aq[4], bk[4];
#pragma unroll
  for (int mi = 0; mi < 4; ++mi) {
    int tk = mi * 16 + l15; if (tk > 48) tk = 0;
    aq[mi] = *(const bf16x8*)(qkv + growof(tk) * 1728 + head * 96 + l4 * 8);
  }
#pragma unroll
  for (int ni = 0; ni < 4; ++ni) {
    int tk = ni * 16 + l15; if (tk > 48) tk = 0;
    bk[ni] = *(const bf16x8*)(qkv + growof(tk) * 1728 + head * 96 + 32 + l4 * 8);
  }

  f32x4 acc[4][4];
#pragma unroll
  for (int mi = 0; mi < 4; ++mi)
#pragma unroll
    for (int ni = 0; ni < 4; ++ni) acc[mi][ni] = (f32x4){0.f, 0.f, 0.f, 0.f};
#pragma unroll
  for (int mi = 0; mi < 4; ++mi)
#pragma unroll
    for (int ni = 0; ni < 4; ++ni)
      acc[mi][ni] = __builtin_amdgcn_mfma_f32_16x16x32_bf16(aq[mi], bk[ni], acc[mi][ni], 0, 0, 0);

  const float scale = 0.17677669529663687f;
  const float* btab = biases + head * 49;
#pragma unroll
  for (int mi = 0; mi < 4; ++mi) {
#pragma unroll
    for (int rr = 0; rr < 4; ++rr) {
      const int i = mi * 16 + l4 * 4 + rr;
      const int ic = i < 49 ? i : 0;
      const int ri = ic / 7, ci = ic - ri * 7;
      float s[4];
#pragma unroll
      for (int ni = 0; ni < 4; ++ni) {
        const int j = ni * 16 + l15;
        if (j < 49) {
          const int rj = j / 7, cj = j - rj * 7;
          s[ni] = acc[mi][ni][rr] * scale + btab[__builtin_abs(ri - rj) * 7 + __builtin_abs(ci - cj)];
        } else {
          s[ni] = -1e30f;
        }
      }
      float m = fmaxf(fmaxf(s[0], s[1]), fmaxf(s[2], s[3]));
#pragma unroll
      for (int d = 1; d < 16; d <<= 1) m = fmaxf(m, __shfl_xor(m, d));
      float sum = 0.f;
#pragma unroll
      for (int ni = 0; ni < 4; ++ni) { s[ni] = __expf(s[ni] - m); sum += s[ni]; }
#pragma unroll
      for (int d = 1; d < 16; d <<= 1) sum += __shfl_xor(sum, d);
      const float inv = 1.0f / sum;
#pragma unroll
      for (int ni = 0; ni < 4; ++ni)
        sP[i][ni * 16 + l15] = __float2bfloat16(s[ni] * inv);
    }
  }
  __syncthreads();

  f32x4 oacc[4][2];
#pragma unroll
  for (int mi = 0; mi < 4; ++mi)
#pragma unroll
    for (int ni = 0; ni < 2; ++ni) oacc[mi][ni] = (f32x4){0.f, 0.f, 0.f, 0.f};
#pragma unroll
  for (int kb = 0; kb < 2; ++kb) {
    bf16x8 ap[4], bv[2];
#pragma unroll
    for (int mi = 0; mi < 4; ++mi) ap[mi] = *(const bf16x8*)&sP[mi * 16 + l15][kb * 32 + l4 * 8];
#pragma unroll
    for (int ni = 0; ni < 2; ++ni) bv[ni] = *(const bf16x8*)&sVT[ni * 16 + l15][kb * 32 + l4 * 8];
#pragma unroll
    for (int mi = 0; mi < 4; ++mi)
#pragma unroll
      for (int ni = 0; ni < 2; ++ni)
        oacc[mi][ni] = __builtin_amdgcn_mfma_f32_16x16x32_bf16(ap[mi], bv[ni], oacc[mi][ni], 0, 0, 0);
  }

#pragma unroll
  for (int mi = 0; mi < 4; ++mi) {
#pragma unroll
    for (int rr = 0; rr < 4; ++rr) {
      const int i = mi * 16 + l4 * 4 + rr;
      if (i < 49) {
        const size_t grow = growof(i);
#pragma unroll
        for (int ni = 0; ni < 2; ++ni)
          o[grow * 576 + head * 32 + ni * 16 + l15] = __float2bfloat16(oacc[mi][ni][rr]);
      }
    }
  }
}

// ---------- fused depthwise conv3x3 + BN + LN2: x1(bf16) -> x2(f32) + xn2(bf16) ----------
__global__ __launch_bounds__(576) void conv_bn_ln_kernel(
    const __hip_bfloat16* __restrict__ x1b, const float* __restrict__ wT,
    const float* __restrict__ st, const float* __restrict__ g,
    const float* __restrict__ bet, float* __restrict__ x2,
    __hip_bfloat16* __restrict__ xn2) {
  __shared__ float sS[576], sSS[576];
  __shared__ float sMV[4][2];
  const int tid = threadIdx.x;
  const int pl = tid / 144, c4 = tid - pl * 144;
  const int p = blockIdx.x * 4 + pl;
  const int b = p / 784, pix = p - b * 784;
  const int i = pix / 28, j = pix - (pix / 28) * 28;
  const int c = c4 * 4;

  float y0 = 0.f, y1 = 0.f, y2v = 0.f, y3 = 0.f;
#pragma unroll
  for (int dh = -1; dh <= 1; ++dh) {
#pragma unroll
    for (int dw = -1; dw <= 1; ++dw) {
      const int ii = i + dh, jj = j + dw;
      if (ii >= 0 && ii < 28 && jj >= 0 && jj < 28) {
        const ushort4 u = *(const ushort4*)&x1b[((size_t)b * 784 + ii * 28 + jj) * 576 + c];
        const f32x4 wv = *(const f32x4*)&wT[((dh + 1) * 3 + (dw + 1)) * 576 + c];
        y0 += __bfloat162float(*(const __hip_bfloat16*)&u.x) * wv[0];
        y1 += __bfloat162float(*(const __hip_bfloat16*)&u.y) * wv[1];
        y2v += __bfloat162float(*(const __hip_bfloat16*)&u.z) * wv[2];
        y3 += __bfloat162float(*(const __hip_bfloat16*)&u.w) * wv[3];
      }
    }
  }
  const f32x4 sc = *(const f32x4*)&st[c];
  const f32x4 tt = *(const f32x4*)&st[576 + c];
  y0 = y0 * sc[0] + tt[0];
  y1 = y1 * sc[1] + tt[1];
  y2v = y2v * sc[2] + tt[2];
  y3 = y3 * sc[3] + tt[3];

  sS[tid] = y0 + y1 + y2v + y3;
  sSS[tid] = y0 * y0 + y1 * y1 + y2v * y2v + y3 * y3;
  __syncthreads();

  const int wv_ = tid >> 6, lane = tid & 63;
  if (wv_ < 4) {
    const int base = wv_ * 144;
    float a  = sS[base + lane] + sS[base + 64 + lane] + (lane < 16 ? sS[base + 128 + lane] : 0.f);
    float a2 = sSS[base + lane] + sSS[base + 64 + lane] + (lane < 16 ? sSS[base + 128 + lane] : 0.f);
#pragma unroll
    for (int o = 32; o; o >>= 1) { a += __shfl_down(a, o); a2 += __shfl_down(a2, o); }
    if (lane == 0) {
      const float m = a * (1.f / 576.f);
      sMV[wv_][0] = m;
      sMV[wv_][1] = rsqrtf(a2 * (1.f / 576.f) - m * m + 1e-5f);
    }
  }
  __syncthreads();

  const float m = sMV[pl][0], rs = sMV[pl][1];
  const size_t rowo = (size_t)b * 784 + pix;
  *(f32x4*)&x2[rowo * 576 + c] = (f32x4){y0, y1, y2v, y3};
  const f32x4 gv = *(const f32x4*)&g[c];
  const f32x4 bv = *(const f32x4*)&bet[c];
  ushort4 ob;
  __hip_bfloat16 h0 = __float2bfloat16((y0 - m) * rs * gv[0] + bv[0]); ob.x = *(ushort*)&h0;
  __hip_bfloat16 h1 = __float2bfloat16((y1 - m) * rs * gv[1] + bv[1]); ob.y = *(ushort*)&h1;
  __hip_bfloat16 h2 = __float2bfloat16((y2v - m) * rs * gv[2] + bv[2]); ob.z = *(ushort*)&h2;
  __hip_bfloat16 h3 = __float2bfloat16((y3 - m) * rs * gv[3] + bv[3]); ob.w = *(ushort*)&h3;
  *(ushort4*)&xn2[rowo * 576 + c] = ob;
}

// ---------- launch ----------
extern "C" void kernel_launch(void* const* d_in, const int* in_sizes, int n_in,
                              void* d_out, int out_size, void* d_ws, size_t ws_size,
                              hipStream_t stream) {
  (void)in_sizes; (void)n_in; (void)out_size; (void)ws_size;
  const float* x      = (const float*)d_in[0];
  const float* ln1g   = (const float*)d_in[1];
  const float* ln1b   = (const float*)d_in[2];
  const float* qkv_w  = (const float*)d_in[3];
  const float* qkv_b  = (const float*)d_in[4];
  const float* biases = (const float*)d_in[5];
  const float* proj_w = (const float*)d_in[6];
  const float* proj_b = (const float*)d_in[7];
  const float* conv_w = (const float*)d_in[8];
  const float* bng    = (const float*)d_in[9];
  const float* bnb    = (const float*)d_in[10];
  const float* bnm    = (const float*)d_in[11];
  const float* bnv    = (const float*)d_in[12];
  const float* ln2g   = (const float*)d_in[13];
  const float* ln2b   = (const float*)d_in[14];
  const float* fc1_w  = (const float*)d_in[15];
  const float* fc1_b  = (const float*)d_in[16];
  const float* fc2_w  = (const float*)d_in[17];
  const float* fc2_b  = (const float*)d_in[18];
  float* out = (float*)d_out;

  const int M = 25088;
  char* ws = (char*)d_ws;
  float* x2 = (float*)ws;
  char* regB = ws + 57802752;
  __hip_bfloat16* qkvb = (__hip_bfloat16*)regB;
  __hip_bfloat16* x1b  = (__hip_bfloat16*)regB;
  __hip_bfloat16* hm   = (__hip_bfloat16*)regB;
  char* regC = ws + 173408256;
  __hip_bfloat16* xn1  = (__hip_bfloat16*)regC;
  __hip_bfloat16* obuf = (__hip_bfloat16*)regC;
  __hip_bfloat16* xn2  = (__hip_bfloat16*)regC;
  char* regD = ws + 202309632;
  __hip_bfloat16* qkvT = (__hip_bfloat16*)regD;
  __hip_bfloat16* projT = (__hip_bfloat16*)(regD + 1990656);
  __hip_bfloat16* fc1T  = (__hip_bfloat16*)(regD + 1990656 + 663552);
  __hip_bfloat16* fc2T  = (__hip_bfloat16*)(regD + 1990656 + 663552 + 2654208);
  float* convT = (float*)(ws + 210272256);
  float* convST = convT + 9 * 576;

  // weight prep
  wt_kernel<<<dim3(1728 / 32, 576 / 32), 256, 0, stream>>>(qkv_w, qkvT, 576, 1728);
  wt_kernel<<<dim3(576 / 32, 576 / 32), 256, 0, stream>>>(proj_w, projT, 576, 576);
  wt_kernel<<<dim3(2304 / 32, 576 / 32), 256, 0, stream>>>(fc1_w, fc1T, 576, 2304);
  wt_kernel<<<dim3(576 / 32, 2304 / 32), 256, 0, stream>>>(fc2_w, fc2T, 2304, 576);
  convprep_kernel<<<(576 * 9 + 255) / 256, 256, 0, stream>>>(conv_w, bng, bnb, bnm, bnv, convT, convST);

  // 1. xn1 = LN1(x) bf16
  ln_bf16_kernel<<<M / 4, 256, 0, stream>>>(x, ln1g, ln1b, xn1);
  // 2. qkv = xn1 @ qkv_w + qkv_b (bf16 out); BN=192, grid 196 x 9
  gemm_bt<192, 0, __hip_bfloat16><<<196 * 9, 256, 0, stream>>>(xn1, qkvT, qkv_b, nullptr, qkvb, M, 1728, 576);
  // 3. attention (low-LDS MFMA)
  attn_mfma_kernel<<<512 * 18, 64, 0, stream>>>(qkvb, biases, obuf);
  // 4. x1 = x + (o @ proj_w + proj_b), stored bf16; BN=64
  gemm_bt<64, 1, __hip_bfloat16><<<196 * 9, 256, 0, stream>>>(obuf, projT, proj_b, x, x1b, M, 576, 576);
  // 5+6. x2 = BN(dwconv(x1)); xn2 = LN2(x2)  (fused)
  conv_bn_ln_kernel<<<M / 4, 576, 0, stream>>>(x1b, convT, convST, ln2g, ln2b, x2, xn2);
  // 7. hm = gelu(xn2 @ fc1_w + fc1_b) bf16; BN=192, grid 196 x 12
  gemm_bt<192, 2, __hip_bfloat16><<<196 * 12, 256, 0, stream>>>(xn2, fc1T, fc1_b, nullptr, hm, M, 2304, 576);
  // 8. out = x2 + (hm @ fc2_w + fc2_b); BN=64
  gemm_bt<64, 1, float><<<196 * 9, 256, 0, stream>>>(hm, fc2T, fc2_b, x2, out, M, 576, 2304);
}

// Round 22
// 477.161 us; speedup vs baseline: 1.9137x; 1.9137x over previous
//
#include <hip/hip_runtime.h>
#include <hip/hip_bf16.h>

typedef __attribute__((ext_vector_type(8))) short bf16x8;
typedef __attribute__((ext_vector_type(4))) float f32x4;

static __device__ __forceinline__ void stf(float* p, size_t i, float v) { p[i] = v; }
static __device__ __forceinline__ void stf(__hip_bfloat16* p, size_t i, float v) { p[i] = __float2bfloat16(v); }

static __device__ __forceinline__ void gload_lds16(const void* g, void* l) {
  __builtin_amdgcn_global_load_lds((const __attribute__((address_space(1))) void*)g,
                                   (__attribute__((address_space(3))) void*)l, 16, 0, 0);
}

// ---------- weight transpose + bf16 convert: W[K][N] f32 -> WT[N][K] bf16 ----------
__global__ void wt_kernel(const float* __restrict__ W, __hip_bfloat16* __restrict__ WT, int K, int N) {
  __shared__ float tile[32][33];
  const int kb = blockIdx.y * 32, nb = blockIdx.x * 32;
  const int tx = threadIdx.x & 31, ty = threadIdx.x >> 5;
#pragma unroll
  for (int i = 0; i < 4; ++i)
    tile[ty + i * 8][tx] = W[(size_t)(kb + ty + i * 8) * N + nb + tx];
  __syncthreads();
#pragma unroll
  for (int i = 0; i < 4; ++i)
    WT[(size_t)(nb + ty + i * 8) * K + kb + tx] = __float2bfloat16(tile[tx][ty + i * 8]);
}

// ---------- conv prep ----------
__global__ void convprep_kernel(const float* __restrict__ w, const float* __restrict__ bng,
                                const float* __restrict__ bnb, const float* __restrict__ bnm,
                                const float* __restrict__ bnv, float* __restrict__ wT,
                                float* __restrict__ st) {
  const int i = blockIdx.x * 256 + threadIdx.x;
  if (i < 576 * 9) {
    const int t = i / 576, c = i - t * 576;
    wT[i] = w[c * 9 + t];
  }
  if (i < 576) {
    const float s = rsqrtf(bnv[i] + 1e-5f) * bng[i];
    st[i] = s;
    st[576 + i] = bnb[i] - bnm[i] * s;
  }
}

// ---------- fused LN -> bf16 ----------
__global__ void ln_bf16_kernel(const float* __restrict__ x, const float* __restrict__ g,
                               const float* __restrict__ b, __hip_bfloat16* __restrict__ y) {
  const int row = blockIdx.x * 4 + (threadIdx.x >> 6);
  const int lane = threadIdx.x & 63;
  const float* p = x + (size_t)row * 576;
  float vals[9];
  float s = 0.f, ss = 0.f;
#pragma unroll
  for (int i = 0; i < 9; ++i) {
    float v = p[lane + i * 64];
    vals[i] = v; s += v; ss += v * v;
  }
#pragma unroll
  for (int o = 32; o; o >>= 1) { s += __shfl_down(s, o); ss += __shfl_down(ss, o); }
  s = __shfl(s, 0); ss = __shfl(ss, 0);
  const float m = s * (1.f / 576.f);
  const float rstd = rsqrtf(ss * (1.f / 576.f) - m * m + 1e-5f);
  __hip_bfloat16* q = y + (size_t)row * 576;
#pragma unroll
  for (int i = 0; i < 9; ++i) {
    const int c = lane + i * 64;
    q[c] = __float2bfloat16((vals[i] - m) * rstd * g[c] + b[c]);
  }
}

// ---------- MFMA GEMM (R16 structure, BN in {64,96}): 128xBN, BK=32 ----------
// BN=64: 24KB LDS, 6 blk/CU (R16-exact, proven best for N=576 ops).
// BN=96: 28KB LDS, 5 blk/CU, intensity 43->61 F/B. VGPR budget (checked after
// R20's BN=192 spill disaster): acc 48 + a 16 + b 12 + addr ~25 = ~100 < 128
// cap at launch_bounds(256,4) -> no spill. B staging = 384 slots -> second
// iteration predicated on t<128 (wave-uniform -> gload_lds well-formed).
// Swizzle f(row)=(row>>1)&3 both-sides; ascending-K accumulation.
// EPI: 0 none, 1 +res, 2 exact GELU
template <int BN, int EPI, typename TO>
__global__ __launch_bounds__(256, (BN == 64 ? 6 : 4)) void gemm_bt(
    const __hip_bfloat16* __restrict__ A, const __hip_bfloat16* __restrict__ BT,
    const float* __restrict__ bias, const float* __restrict__ res, TO* __restrict__ C,
    int M, int N, int K) {
  constexpr int NI = BN / 32;          // frags per wave (wave tile 64 x BN/2)
  constexpr int BSLOTS = BN * 4;       // B stage slots (8 bf16 each)
  __shared__ __hip_bfloat16 sA[2][128 * 32];
  __shared__ __hip_bfloat16 sB[2][BN * 32];
  const int t = threadIdx.x;
  const int lane = t & 63;
  const int w = t >> 6;
  const int nwg = gridDim.x;
  const int qq = nwg >> 3, r = nwg & 7;
  const int xcd = blockIdx.x & 7, lidx = blockIdx.x >> 3;
  const int wgid = (xcd < r ? xcd * (qq + 1) : r * (qq + 1) + (xcd - r) * qq) + lidx;
  const int nx = N / BN;
  const int bm = (wgid / nx) * 128, bn = (wgid % nx) * BN;
  const int wm = (w >> 1) * 64, wn = (w & 1) * (BN / 2);
  const int l15 = lane & 15, l4 = lane >> 4;
  const int wave_base = t & ~63;

  f32x4 acc[4][NI];
#pragma unroll
  for (int mi = 0; mi < 4; ++mi)
#pragma unroll
    for (int ni = 0; ni < NI; ++ni) acc[mi][ni] = (f32x4){0.f, 0.f, 0.f, 0.f};

  auto stage = [&](int buf, int k0) {
#pragma unroll
    for (int i = 0; i < 2; ++i) {
      const int slot = i * 256 + t;
      const int row = slot >> 2, kst = slot & 3;
      const int ksrc = kst ^ ((row >> 1) & 3);
      gload_lds16(A + (size_t)(bm + row) * K + k0 + ksrc * 8,
                  sA[buf] + (i * 256 + wave_base) * 8);
    }
#pragma unroll
    for (int i = 0; i < (BSLOTS + 255) / 256; ++i) {
      const int slot = i * 256 + t;
      if (BSLOTS % 256 == 0 || slot < BSLOTS) {
        const int row = slot >> 2, kst = slot & 3;
        const int ksrc = kst ^ ((row >> 1) & 3);
        gload_lds16(BT + (size_t)(bn + row) * K + k0 + ksrc * 8,
                    sB[buf] + (i * 256 + wave_base) * 8);
      }
    }
  };

  auto compute = [&](int buf) {
    bf16x8 a[4], b[NI];
#pragma unroll
    for (int mi = 0; mi < 4; ++mi) {
      const int row = wm + mi * 16 + l15;
      a[mi] = *(const bf16x8*)(&sA[buf][row * 32 + ((l4 ^ ((row >> 1) & 3)) * 8)]);
    }
#pragma unroll
    for (int ni = 0; ni < NI; ++ni) {
      const int row = wn + ni * 16 + l15;
      b[ni] = *(const bf16x8*)(&sB[buf][row * 32 + ((l4 ^ ((row >> 1) & 3)) * 8)]);
    }
#pragma unroll
    for (int mi = 0; mi < 4; ++mi)
#pragma unroll
      for (int ni = 0; ni < NI; ++ni)
        acc[mi][ni] = __builtin_amdgcn_mfma_f32_16x16x32_bf16(a[mi], b[ni], acc[mi][ni], 0, 0, 0);
  };

  const int nt = K >> 5;
  stage(0, 0);
  __syncthreads();
  int cur = 0;
  for (int tt = 0; tt < nt - 1; ++tt) {
    stage(cur ^ 1, (tt + 1) << 5);
    compute(cur);
    __syncthreads();
    cur ^= 1;
  }
  compute(cur);

#pragma unroll
  for (int mi = 0; mi < 4; ++mi) {
    const int mrow = bm + wm + mi * 16 + l4 * 4;
#pragma unroll
    for (int ni = 0; ni < NI; ++ni) {
      const int col = bn + wn + ni * 16 + l15;
      const float bv = bias[col];
#pragma unroll
      for (int r2 = 0; r2 < 4; ++r2) {
        const size_t idx = (size_t)(mrow + r2) * N + col;
        float v = acc[mi][ni][r2] + bv;
        if (EPI == 1) v += res[idx];
        if (EPI == 2) v = 0.5f * v * (1.0f + erff(v * 0.70710678118654752f));
        stf(C, idx, v);
      }
    }
  }
}

// ---------- MFMA windowed attention, low-LDS (R12 config, kept) ----------
__global__ __launch_bounds__(64) void attn_mfma_kernel(
    const __hip_bfloat16* __restrict__ qkv, const float* __restrict__ biases,
    __hip_bfloat16* __restrict__ o) {
  __shared__ __hip_bfloat16 sVT[32][72];
  __shared__ __hip_bfloat16 sP[64][72];

  const int wid  = blockIdx.x / 18;
  const int head = blockIdx.x - wid * 18;
  const int b  = wid >> 4;
  const int wi = wid & 15;
  const int wh = wi >> 2, wwc = wi & 3;
  const int lane = threadIdx.x;
  const int l15 = lane & 15, l4 = lane >> 4;

  auto growof = [&](int tkn) -> size_t {
    const int r = tkn / 7, c = tkn - r * 7;
    return (size_t)b * 784 + (size_t)((wh * 7 + r) * 28 + wwc * 7 + c);
  };

  for (int idx = lane; idx < 49 * 4; idx += 64) {
    const int tkn = idx >> 2, part = idx & 3;
    const bf16x8 v = *(const bf16x8*)(qkv + growof(tkn) * 1728 + head * 96 + 64 + part * 8);
    const short* sv = (const short*)&v;
#pragma unroll
    for (int e = 0; e < 8; ++e)
      sVT[part * 8 + e][tkn] = *(const __hip_bfloat16*)&sv[e];
  }
  for (int idx = lane; idx < 32 * 15; idx += 64) {
    const int d = idx / 15, tt = 49 + (idx - d * 15);
    sVT[d][tt] = __float2bfloat16(0.0f);
  }

  bf16x8 aq[4], bk[4];
#pragma unroll
  for (int mi = 0; mi < 4; ++mi) {
    int tk = mi * 16 + l15; if (tk > 48) tk = 0;
    aq[mi] = *(const bf16x8*)(qkv + growof(tk) * 1728 + head * 96 + l4 * 8);
  }
#pragma unroll
  for (int ni = 0; ni < 4; ++ni) {
    int tk = ni * 16 + l15; if (tk > 48) tk = 0;
    bk[ni] = *(const bf16x8*)(qkv + growof(tk) * 1728 + head * 96 + 32 + l4 * 8);
  }

  f32x4 acc[4][4];
#pragma unroll
  for (int mi = 0; mi < 4; ++mi)
#pragma unroll
    for (int ni = 0; ni < 4; ++ni) acc[mi][ni] = (f32x4){0.f, 0.f, 0.f, 0.f};
#pragma unroll
  for (int mi = 0; mi < 4; ++mi)
#pragma unroll
    for (int ni = 0; ni < 4; ++ni)
      acc[mi][ni] = __builtin_amdgcn_mfma_f32_16x16x32_bf16(aq[mi], bk[ni], acc[mi][ni], 0, 0, 0);

  const float scale = 0.17677669529663687f;
  const float* btab = biases + head * 49;
#pragma unroll
  for (int mi = 0; mi < 4; ++mi) {
#pragma unroll
    for (int rr = 0; rr < 4; ++rr) {
      const int i = mi * 16 + l4 * 4 + rr;
      const int ic = i < 49 ? i : 0;
      const int ri = ic / 7, ci = ic - ri * 7;
      float s[4];
#pragma unroll
      for (int ni = 0; ni < 4; ++ni) {
        const int j = ni * 16 + l15;
        if (j < 49) {
          const int rj = j / 7, cj = j - rj * 7;
          s[ni] = acc[mi][ni][rr] * scale + btab[__builtin_abs(ri - rj) * 7 + __builtin_abs(ci - cj)];
        } else {
          s[ni] = -1e30f;
        }
      }
      float m = fmaxf(fmaxf(s[0], s[1]), fmaxf(s[2], s[3]));
#pragma unroll
      for (int d = 1; d < 16; d <<= 1) m = fmaxf(m, __shfl_xor(m, d));
      float sum = 0.f;
#pragma unroll
      for (int ni = 0; ni < 4; ++ni) { s[ni] = __expf(s[ni] - m); sum += s[ni]; }
#pragma unroll
      for (int d = 1; d < 16; d <<= 1) sum += __shfl_xor(sum, d);
      const float inv = 1.0f / sum;
#pragma unroll
      for (int ni = 0; ni < 4; ++ni)
        sP[i][ni * 16 + l15] = __float2bfloat16(s[ni] * inv);
    }
  }
  __syncthreads();

  f32x4 oacc[4][2];
#pragma unroll
  for (int mi = 0; mi < 4; ++mi)
#pragma unroll
    for (int ni = 0; ni < 2; ++ni) oacc[mi][ni] = (f32x4){0.f, 0.f, 0.f, 0.f};
#pragma unroll
  for (int kb = 0; kb < 2; ++kb) {
    bf16x8 ap[4], bv[2];
#pragma unroll
    for (int mi = 0; mi < 4; ++mi) ap[mi] = *(const bf16x8*)&sP[mi * 16 + l15][kb * 32 + l4 * 8];
#pragma unroll
    for (int ni = 0; ni < 2; ++ni) bv[ni] = *(const bf16x8*)&sVT[ni * 16 + l15][kb * 32 + l4 * 8];
#pragma unroll
    for (int mi = 0; mi < 4; ++mi)
#pragma unroll
      for (int ni = 0; ni < 2; ++ni)
        oacc[mi][ni] = __builtin_amdgcn_mfma_f32_16x16x32_bf16(ap[mi], bv[ni], oacc[mi][ni], 0, 0, 0);
  }

#pragma unroll
  for (int mi = 0; mi < 4; ++mi) {
#pragma unroll
    for (int rr = 0; rr < 4; ++rr) {
      const int i = mi * 16 + l4 * 4 + rr;
      if (i < 49) {
        const size_t grow = growof(i);
#pragma unroll
        for (int ni = 0; ni < 2; ++ni)
          o[grow * 576 + head * 32 + ni * 16 + l15] = __float2bfloat16(oacc[mi][ni][rr]);
      }
    }
  }
}

// ---------- fused depthwise conv3x3 + BN + LN2: x1(bf16) -> x2(f32) + xn2(bf16) ----------
__global__ __launch_bounds__(576) void conv_bn_ln_kernel(
    const __hip_bfloat16* __restrict__ x1b, const float* __restrict__ wT,
    const float* __restrict__ st, const float* __restrict__ g,
    const float* __restrict__ bet, float* __restrict__ x2,
    __hip_bfloat16* __restrict__ xn2) {
  __shared__ float sS[576], sSS[576];
  __shared__ float sMV[4][2];
  const int tid = threadIdx.x;
  const int pl = tid / 144, c4 = tid - pl * 144;
  const int p = blockIdx.x * 4 + pl;
  const int b = p / 784, pix = p - b * 784;
  const int i = pix / 28, j = pix - (pix / 28) * 28;
  const int c = c4 * 4;

  float y0 = 0.f, y1 = 0.f, y2v = 0.f, y3 = 0.f;
#pragma unroll
  for (int dh = -1; dh <= 1; ++dh) {
#pragma unroll
    for (int dw = -1; dw <= 1; ++dw) {
      const int ii = i + dh, jj = j + dw;
      if (ii >= 0 && ii < 28 && jj >= 0 && jj < 28) {
        const ushort4 u = *(const ushort4*)&x1b[((size_t)b * 784 + ii * 28 + jj) * 576 + c];
        const f32x4 wv = *(const f32x4*)&wT[((dh + 1) * 3 + (dw + 1)) * 576 + c];
        y0 += __bfloat162float(*(const __hip_bfloat16*)&u.x) * wv[0];
        y1 += __bfloat162float(*(const __hip_bfloat16*)&u.y) * wv[1];
        y2v += __bfloat162float(*(const __hip_bfloat16*)&u.z) * wv[2];
        y3 += __bfloat162float(*(const __hip_bfloat16*)&u.w) * wv[3];
      }
    }
  }
  const f32x4 sc = *(const f32x4*)&st[c];
  const f32x4 tt = *(const f32x4*)&st[576 + c];
  y0 = y0 * sc[0] + tt[0];
  y1 = y1 * sc[1] + tt[1];
  y2v = y2v * sc[2] + tt[2];
  y3 = y3 * sc[3] + tt[3];

  sS[tid] = y0 + y1 + y2v + y3;
  sSS[tid] = y0 * y0 + y1 * y1 + y2v * y2v + y3 * y3;
  __syncthreads();

  const int wv_ = tid >> 6, lane = tid & 63;
  if (wv_ < 4) {
    const int base = wv_ * 144;
    float a  = sS[base + lane] + sS[base + 64 + lane] + (lane < 16 ? sS[base + 128 + lane] : 0.f);
    float a2 = sSS[base + lane] + sSS[base + 64 + lane] + (lane < 16 ? sSS[base + 128 + lane] : 0.f);
#pragma unroll
    for (int o = 32; o; o >>= 1) { a += __shfl_down(a, o); a2 += __shfl_down(a2, o); }
    if (lane == 0) {
      const float m = a * (1.f / 576.f);
      sMV[wv_][0] = m;
      sMV[wv_][1] = rsqrtf(a2 * (1.f / 576.f) - m * m + 1e-5f);
    }
  }
  __syncthreads();

  const float m = sMV[pl][0], rs = sMV[pl][1];
  const size_t rowo = (size_t)b * 784 + pix;
  *(f32x4*)&x2[rowo * 576 + c] = (f32x4){y0, y1, y2v, y3};
  const f32x4 gv = *(const f32x4*)&g[c];
  const f32x4 bv = *(const f32x4*)&bet[c];
  ushort4 ob;
  __hip_bfloat16 h0 = __float2bfloat16((y0 - m) * rs * gv[0] + bv[0]); ob.x = *(ushort*)&h0;
  __hip_bfloat16 h1 = __float2bfloat16((y1 - m) * rs * gv[1] + bv[1]); ob.y = *(ushort*)&h1;
  __hip_bfloat16 h2 = __float2bfloat16((y2v - m) * rs * gv[2] + bv[2]); ob.z = *(ushort*)&h2;
  __hip_bfloat16 h3 = __float2bfloat16((y3 - m) * rs * gv[3] + bv[3]); ob.w = *(ushort*)&h3;
  *(ushort4*)&xn2[rowo * 576 + c] = ob;
}

// ---------- launch ----------
extern "C" void kernel_launch(void* const* d_in, const int* in_sizes, int n_in,
                              void* d_out, int out_size, void* d_ws, size_t ws_size,
                              hipStream_t stream) {
  (void)in_sizes; (void)n_in; (void)out_size; (void)ws_size;
  const float* x      = (const float*)d_in[0];
  const float* ln1g   = (const float*)d_in[1];
  const float* ln1b   = (const float*)d_in[2];
  const float* qkv_w  = (const float*)d_in[3];
  const float* qkv_b  = (const float*)d_in[4];
  const float* biases = (const float*)d_in[5];
  const float* proj_w = (const float*)d_in[6];
  const float* proj_b = (const float*)d_in[7];
  const float* conv_w = (const float*)d_in[8];
  const float* bng    = (const float*)d_in[9];
  const float* bnb    = (const float*)d_in[10];
  const float* bnm    = (const float*)d_in[11];
  const float* bnv    = (const float*)d_in[12];
  const float* ln2g   = (const float*)d_in[13];
  const float* ln2b   = (const float*)d_in[14];
  const float* fc1_w  = (const float*)d_in[15];
  const float* fc1_b  = (const float*)d_in[16];
  const float* fc2_w  = (const float*)d_in[17];
  const float* fc2_b  = (const float*)d_in[18];
  float* out = (float*)d_out;

  const int M = 25088;
  char* ws = (char*)d_ws;
  float* x2 = (float*)ws;
  char* regB = ws + 57802752;
  __hip_bfloat16* qkvb = (__hip_bfloat16*)regB;
  __hip_bfloat16* x1b  = (__hip_bfloat16*)regB;
  __hip_bfloat16* hm   = (__hip_bfloat16*)regB;
  char* regC = ws + 173408256;
  __hip_bfloat16* xn1  = (__hip_bfloat16*)regC;
  __hip_bfloat16* obuf = (__hip_bfloat16*)regC;
  __hip_bfloat16* xn2  = (__hip_bfloat16*)regC;
  char* regD = ws + 202309632;
  __hip_bfloat16* qkvT = (__hip_bfloat16*)regD;
  __hip_bfloat16* projT = (__hip_bfloat16*)(regD + 1990656);
  __hip_bfloat16* fc1T  = (__hip_bfloat16*)(regD + 1990656 + 663552);
  __hip_bfloat16* fc2T  = (__hip_bfloat16*)(regD + 1990656 + 663552 + 2654208);
  float* convT = (float*)(ws + 210272256);
  float* convST = convT + 9 * 576;

  // weight prep
  wt_kernel<<<dim3(1728 / 32, 576 / 32), 256, 0, stream>>>(qkv_w, qkvT, 576, 1728);
  wt_kernel<<<dim3(576 / 32, 576 / 32), 256, 0, stream>>>(proj_w, projT, 576, 576);
  wt_kernel<<<dim3(2304 / 32, 576 / 32), 256, 0, stream>>>(fc1_w, fc1T, 576, 2304);
  wt_kernel<<<dim3(576 / 32, 2304 / 32), 256, 0, stream>>>(fc2_w, fc2T, 2304, 576);
  convprep_kernel<<<(576 * 9 + 255) / 256, 256, 0, stream>>>(conv_w, bng, bnb, bnm, bnv, convT, convST);

  // 1. xn1 = LN1(x) bf16
  ln_bf16_kernel<<<M / 4, 256, 0, stream>>>(x, ln1g, ln1b, xn1);
  // 2. qkv = xn1 @ qkv_w + qkv_b (bf16 out); BN=96, grid 196 x 18
  gemm_bt<96, 0, __hip_bfloat16><<<196 * 18, 256, 0, stream>>>(xn1, qkvT, qkv_b, nullptr, qkvb, M, 1728, 576);
  // 3. attention (low-LDS MFMA)
  attn_mfma_kernel<<<512 * 18, 64, 0, stream>>>(qkvb, biases, obuf);
  // 4. x1 = x + (o @ proj_w + proj_b), stored bf16; BN=64
  gemm_bt<64, 1, __hip_bfloat16><<<196 * 9, 256, 0, stream>>>(obuf, projT, proj_b, x, x1b, M, 576, 576);
  // 5+6. x2 = BN(dwconv(x1)); xn2 = LN2(x2)  (fused)
  conv_bn_ln_kernel<<<M / 4, 576, 0, stream>>>(x1b, convT, convST, ln2g, ln2b, x2, xn2);
  // 7. hm = gelu(xn2 @ fc1_w + fc1_b) bf16; BN=96, grid 196 x 24
  gemm_bt<96, 2, __hip_bfloat16><<<196 * 24, 256, 0, stream>>>(xn2, fc1T, fc1_b, nullptr, hm, M, 2304, 576);
  // 8. out = x2 + (hm @ fc2_w + fc2_b); BN=64
  gemm_bt<64, 1, float><<<196 * 9, 256, 0, stream>>>(hm, fc2T, fc2_b, x2, out, M, 576, 2304);
}

// Round 23
// 476.627 us; speedup vs baseline: 1.9158x; 1.0011x over previous
//
#include <hip/hip_runtime.h>
#include <hip/hip_bf16.h>

typedef __attribute__((ext_vector_type(8))) short bf16x8;
typedef __attribute__((ext_vector_type(4))) float f32x4;

static __device__ __forceinline__ void stf(float* p, size_t i, float v) { p[i] = v; }
static __device__ __forceinline__ void stf(__hip_bfloat16* p, size_t i, float v) { p[i] = __float2bfloat16(v); }

static __device__ __forceinline__ void gload_lds16(const void* g, void* l) {
  __builtin_amdgcn_global_load_lds((const __attribute__((address_space(1))) void*)g,
                                   (__attribute__((address_space(3))) void*)l, 16, 0, 0);
}

// ---------- weight transpose + bf16 convert: W[K][N] f32 -> WT[N][K] bf16 ----------
__global__ void wt_kernel(const float* __restrict__ W, __hip_bfloat16* __restrict__ WT, int K, int N) {
  __shared__ float tile[32][33];
  const int kb = blockIdx.y * 32, nb = blockIdx.x * 32;
  const int tx = threadIdx.x & 31, ty = threadIdx.x >> 5;
#pragma unroll
  for (int i = 0; i < 4; ++i)
    tile[ty + i * 8][tx] = W[(size_t)(kb + ty + i * 8) * N + nb + tx];
  __syncthreads();
#pragma unroll
  for (int i = 0; i < 4; ++i)
    WT[(size_t)(nb + ty + i * 8) * K + kb + tx] = __float2bfloat16(tile[tx][ty + i * 8]);
}

// ---------- conv prep ----------
__global__ void convprep_kernel(const float* __restrict__ w, const float* __restrict__ bng,
                                const float* __restrict__ bnb, const float* __restrict__ bnm,
                                const float* __restrict__ bnv, float* __restrict__ wT,
                                float* __restrict__ st) {
  const int i = blockIdx.x * 256 + threadIdx.x;
  if (i < 576 * 9) {
    const int t = i / 576, c = i - t * 576;
    wT[i] = w[c * 9 + t];
  }
  if (i < 576) {
    const float s = rsqrtf(bnv[i] + 1e-5f) * bng[i];
    st[i] = s;
    st[576 + i] = bnb[i] - bnm[i] * s;
  }
}

// ---------- fused LN -> bf16 ----------
__global__ void ln_bf16_kernel(const float* __restrict__ x, const float* __restrict__ g,
                               const float* __restrict__ b, __hip_bfloat16* __restrict__ y) {
  const int row = blockIdx.x * 4 + (threadIdx.x >> 6);
  const int lane = threadIdx.x & 63;
  const float* p = x + (size_t)row * 576;
  float vals[9];
  float s = 0.f, ss = 0.f;
#pragma unroll
  for (int i = 0; i < 9; ++i) {
    float v = p[lane + i * 64];
    vals[i] = v; s += v; ss += v * v;
  }
#pragma unroll
  for (int o = 32; o; o >>= 1) { s += __shfl_down(s, o); ss += __shfl_down(ss, o); }
  s = __shfl(s, 0); ss = __shfl(ss, 0);
  const float m = s * (1.f / 576.f);
  const float rstd = rsqrtf(ss * (1.f / 576.f) - m * m + 1e-5f);
  __hip_bfloat16* q = y + (size_t)row * 576;
#pragma unroll
  for (int i = 0; i < 9; ++i) {
    const int c = lane + i * 64;
    q[c] = __float2bfloat16((vals[i] - m) * rstd * g[c] + b[c]);
  }
}

// ---------- MFMA GEMM (R16 structure, BN in {64,96}): 128xBN, BK=32 ----------
// BN=96 (R22-proven): 28KB LDS, 5 blk/CU, intensity 61 F/B, ~100 VGPR no spill.
// BN=64 (R16-exact): 24KB LDS, 6 blk/CU. Swizzle f(row)=(row>>1)&3 both-sides;
// ascending-K accumulation (bit-identical across BN).
// EPI: 0 none, 1 +res, 2 exact GELU
template <int BN, int EPI, typename TO>
__global__ __launch_bounds__(256, (BN == 64 ? 6 : 4)) void gemm_bt(
    const __hip_bfloat16* __restrict__ A, const __hip_bfloat16* __restrict__ BT,
    const float* __restrict__ bias, const float* __restrict__ res, TO* __restrict__ C,
    int M, int N, int K) {
  constexpr int NI = BN / 32;          // frags per wave (wave tile 64 x BN/2)
  constexpr int BSLOTS = BN * 4;       // B stage slots (8 bf16 each)
  __shared__ __hip_bfloat16 sA[2][128 * 32];
  __shared__ __hip_bfloat16 sB[2][BN * 32];
  const int t = threadIdx.x;
  const int lane = t & 63;
  const int w = t >> 6;
  const int nwg = gridDim.x;
  const int qq = nwg >> 3, r = nwg & 7;
  const int xcd = blockIdx.x & 7, lidx = blockIdx.x >> 3;
  const int wgid = (xcd < r ? xcd * (qq + 1) : r * (qq + 1) + (xcd - r) * qq) + lidx;
  const int nx = N / BN;
  const int bm = (wgid / nx) * 128, bn = (wgid % nx) * BN;
  const int wm = (w >> 1) * 64, wn = (w & 1) * (BN / 2);
  const int l15 = lane & 15, l4 = lane >> 4;
  const int wave_base = t & ~63;

  f32x4 acc[4][NI];
#pragma unroll
  for (int mi = 0; mi < 4; ++mi)
#pragma unroll
    for (int ni = 0; ni < NI; ++ni) acc[mi][ni] = (f32x4){0.f, 0.f, 0.f, 0.f};

  auto stage = [&](int buf, int k0) {
#pragma unroll
    for (int i = 0; i < 2; ++i) {
      const int slot = i * 256 + t;
      const int row = slot >> 2, kst = slot & 3;
      const int ksrc = kst ^ ((row >> 1) & 3);
      gload_lds16(A + (size_t)(bm + row) * K + k0 + ksrc * 8,
                  sA[buf] + (i * 256 + wave_base) * 8);
    }
#pragma unroll
    for (int i = 0; i < (BSLOTS + 255) / 256; ++i) {
      const int slot = i * 256 + t;
      if (BSLOTS % 256 == 0 || slot < BSLOTS) {
        const int row = slot >> 2, kst = slot & 3;
        const int ksrc = kst ^ ((row >> 1) & 3);
        gload_lds16(BT + (size_t)(bn + row) * K + k0 + ksrc * 8,
                    sB[buf] + (i * 256 + wave_base) * 8);
      }
    }
  };

  auto compute = [&](int buf) {
    bf16x8 a[4], b[NI];
#pragma unroll
    for (int mi = 0; mi < 4; ++mi) {
      const int row = wm + mi * 16 + l15;
      a[mi] = *(const bf16x8*)(&sA[buf][row * 32 + ((l4 ^ ((row >> 1) & 3)) * 8)]);
    }
#pragma unroll
    for (int ni = 0; ni < NI; ++ni) {
      const int row = wn + ni * 16 + l15;
      b[ni] = *(const bf16x8*)(&sB[buf][row * 32 + ((l4 ^ ((row >> 1) & 3)) * 8)]);
    }
#pragma unroll
    for (int mi = 0; mi < 4; ++mi)
#pragma unroll
      for (int ni = 0; ni < NI; ++ni)
        acc[mi][ni] = __builtin_amdgcn_mfma_f32_16x16x32_bf16(a[mi], b[ni], acc[mi][ni], 0, 0, 0);
  };

  const int nt = K >> 5;
  stage(0, 0);
  __syncthreads();
  int cur = 0;
  for (int tt = 0; tt < nt - 1; ++tt) {
    stage(cur ^ 1, (tt + 1) << 5);
    compute(cur);
    __syncthreads();
    cur ^= 1;
  }
  compute(cur);

#pragma unroll
  for (int mi = 0; mi < 4; ++mi) {
    const int mrow = bm + wm + mi * 16 + l4 * 4;
#pragma unroll
    for (int ni = 0; ni < NI; ++ni) {
      const int col = bn + wn + ni * 16 + l15;
      const float bv = bias[col];
#pragma unroll
      for (int r2 = 0; r2 < 4; ++r2) {
        const size_t idx = (size_t)(mrow + r2) * N + col;
        float v = acc[mi][ni][r2] + bv;
        if (EPI == 1) v += res[idx];
        if (EPI == 2) v = 0.5f * v * (1.0f + erff(v * 0.70710678118654752f));
        stf(C, idx, v);
      }
    }
  }
}

// ---------- MFMA windowed attention, low-LDS (R12 config, kept) ----------
__global__ __launch_bounds__(64) void attn_mfma_kernel(
    const __hip_bfloat16* __restrict__ qkv, const float* __restrict__ biases,
    __hip_bfloat16* __restrict__ o) {
  __shared__ __hip_bfloat16 sVT[32][72];
  __shared__ __hip_bfloat16 sP[64][72];

  const int wid  = blockIdx.x / 18;
  const int head = blockIdx.x - wid * 18;
  const int b  = wid >> 4;
  const int wi = wid & 15;
  const int wh = wi >> 2, wwc = wi & 3;
  const int lane = threadIdx.x;
  const int l15 = lane & 15, l4 = lane >> 4;

  auto growof = [&](int tkn) -> size_t {
    const int r = tkn / 7, c = tkn - r * 7;
    return (size_t)b * 784 + (size_t)((wh * 7 + r) * 28 + wwc * 7 + c);
  };

  for (int idx = lane; idx < 49 * 4; idx += 64) {
    const int tkn = idx >> 2, part = idx & 3;
    const bf16x8 v = *(const bf16x8*)(qkv + growof(tkn) * 1728 + head * 96 + 64 + part * 8);
    const short* sv = (const short*)&v;
#pragma unroll
    for (int e = 0; e < 8; ++e)
      sVT[part * 8 + e][tkn] = *(const __hip_bfloat16*)&sv[e];
  }
  for (int idx = lane; idx < 32 * 15; idx += 64) {
    const int d = idx / 15, tt = 49 + (idx - d * 15);
    sVT[d][tt] = __float2bfloat16(0.0f);
  }

  bf16x8 aq[4], bk[4];
#pragma unroll
  for (int mi = 0; mi < 4; ++mi) {
    int tk = mi * 16 + l15; if (tk > 48) tk = 0;
    aq[mi] = *(const bf16x8*)(qkv + growof(tk) * 1728 + head * 96 + l4 * 8);
  }
#pragma unroll
  for (int ni = 0; ni < 4; ++ni) {
    int tk = ni * 16 + l15; if (tk > 48) tk = 0;
    bk[ni] = *(const bf16x8*)(qkv + growof(tk) * 1728 + head * 96 + 32 + l4 * 8);
  }

  f32x4 acc[4][4];
#pragma unroll
  for (int mi = 0; mi < 4; ++mi)
#pragma unroll
    for (int ni = 0; ni < 4; ++ni) acc[mi][ni] = (f32x4){0.f, 0.f, 0.f, 0.f};
#pragma unroll
  for (int mi = 0; mi < 4; ++mi)
#pragma unroll
    for (int ni = 0; ni < 4; ++ni)
      acc[mi][ni] = __builtin_amdgcn_mfma_f32_16x16x32_bf16(aq[mi], bk[ni], acc[mi][ni], 0, 0, 0);

  const float scale = 0.17677669529663687f;
  const float* btab = biases + head * 49;
#pragma unroll
  for (int mi = 0; mi < 4; ++mi) {
#pragma unroll
    for (int rr = 0; rr < 4; ++rr) {
      const int i = mi * 16 + l4 * 4 + rr;
      const int ic = i < 49 ? i : 0;
      const int ri = ic / 7, ci = ic - ri * 7;
      float s[4];
#pragma unroll
      for (int ni = 0; ni < 4; ++ni) {
        const int j = ni * 16 + l15;
        if (j < 49) {
          const int rj = j / 7, cj = j - rj * 7;
          s[ni] = acc[mi][ni][rr] * scale + btab[__builtin_abs(ri - rj) * 7 + __builtin_abs(ci - cj)];
        } else {
          s[ni] = -1e30f;
        }
      }
      float m = fmaxf(fmaxf(s[0], s[1]), fmaxf(s[2], s[3]));
#pragma unroll
      for (int d = 1; d < 16; d <<= 1) m = fmaxf(m, __shfl_xor(m, d));
      float sum = 0.f;
#pragma unroll
      for (int ni = 0; ni < 4; ++ni) { s[ni] = __expf(s[ni] - m); sum += s[ni]; }
#pragma unroll
      for (int d = 1; d < 16; d <<= 1) sum += __shfl_xor(sum, d);
      const float inv = 1.0f / sum;
#pragma unroll
      for (int ni = 0; ni < 4; ++ni)
        sP[i][ni * 16 + l15] = __float2bfloat16(s[ni] * inv);
    }
  }
  __syncthreads();

  f32x4 oacc[4][2];
#pragma unroll
  for (int mi = 0; mi < 4; ++mi)
#pragma unroll
    for (int ni = 0; ni < 2; ++ni) oacc[mi][ni] = (f32x4){0.f, 0.f, 0.f, 0.f};
#pragma unroll
  for (int kb = 0; kb < 2; ++kb) {
    bf16x8 ap[4], bv[2];
#pragma unroll
    for (int mi = 0; mi < 4; ++mi) ap[mi] = *(const bf16x8*)&sP[mi * 16 + l15][kb * 32 + l4 * 8];
#pragma unroll
    for (int ni = 0; ni < 2; ++ni) bv[ni] = *(const bf16x8*)&sVT[ni * 16 + l15][kb * 32 + l4 * 8];
#pragma unroll
    for (int mi = 0; mi < 4; ++mi)
#pragma unroll
      for (int ni = 0; ni < 2; ++ni)
        oacc[mi][ni] = __builtin_amdgcn_mfma_f32_16x16x32_bf16(ap[mi], bv[ni], oacc[mi][ni], 0, 0, 0);
  }

#pragma unroll
  for (int mi = 0; mi < 4; ++mi) {
#pragma unroll
    for (int rr = 0; rr < 4; ++rr) {
      const int i = mi * 16 + l4 * 4 + rr;
      if (i < 49) {
        const size_t grow = growof(i);
#pragma unroll
        for (int ni = 0; ni < 2; ++ni)
          o[grow * 576 + head * 32 + ni * 16 + l15] = __float2bfloat16(oacc[mi][ni][rr]);
      }
    }
  }
}

// ---------- fused depthwise conv3x3 + BN + LN2: x1(bf16) -> x2(f32) + xn2(bf16) ----------
__global__ __launch_bounds__(576) void conv_bn_ln_kernel(
    const __hip_bfloat16* __restrict__ x1b, const float* __restrict__ wT,
    const float* __restrict__ st, const float* __restrict__ g,
    const float* __restrict__ bet, float* __restrict__ x2,
    __hip_bfloat16* __restrict__ xn2) {
  __shared__ float sS[576], sSS[576];
  __shared__ float sMV[4][2];
  const int tid = threadIdx.x;
  const int pl = tid / 144, c4 = tid - pl * 144;
  const int p = blockIdx.x * 4 + pl;
  const int b = p / 784, pix = p - b * 784;
  const int i = pix / 28, j = pix - (pix / 28) * 28;
  const int c = c4 * 4;

  float y0 = 0.f, y1 = 0.f, y2v = 0.f, y3 = 0.f;
#pragma unroll
  for (int dh = -1; dh <= 1; ++dh) {
#pragma unroll
    for (int dw = -1; dw <= 1; ++dw) {
      const int ii = i + dh, jj = j + dw;
      if (ii >= 0 && ii < 28 && jj >= 0 && jj < 28) {
        const ushort4 u = *(const ushort4*)&x1b[((size_t)b * 784 + ii * 28 + jj) * 576 + c];
        const f32x4 wv = *(const f32x4*)&wT[((dh + 1) * 3 + (dw + 1)) * 576 + c];
        y0 += __bfloat162float(*(const __hip_bfloat16*)&u.x) * wv[0];
        y1 += __bfloat162float(*(const __hip_bfloat16*)&u.y) * wv[1];
        y2v += __bfloat162float(*(const __hip_bfloat16*)&u.z) * wv[2];
        y3 += __bfloat162float(*(const __hip_bfloat16*)&u.w) * wv[3];
      }
    }
  }
  const f32x4 sc = *(const f32x4*)&st[c];
  const f32x4 tt = *(const f32x4*)&st[576 + c];
  y0 = y0 * sc[0] + tt[0];
  y1 = y1 * sc[1] + tt[1];
  y2v = y2v * sc[2] + tt[2];
  y3 = y3 * sc[3] + tt[3];

  sS[tid] = y0 + y1 + y2v + y3;
  sSS[tid] = y0 * y0 + y1 * y1 + y2v * y2v + y3 * y3;
  __syncthreads();

  const int wv_ = tid >> 6, lane = tid & 63;
  if (wv_ < 4) {
    const int base = wv_ * 144;
    float a  = sS[base + lane] + sS[base + 64 + lane] + (lane < 16 ? sS[base + 128 + lane] : 0.f);
    float a2 = sSS[base + lane] + sSS[base + 64 + lane] + (lane < 16 ? sSS[base + 128 + lane] : 0.f);
#pragma unroll
    for (int o = 32; o; o >>= 1) { a += __shfl_down(a, o); a2 += __shfl_down(a2, o); }
    if (lane == 0) {
      const float m = a * (1.f / 576.f);
      sMV[wv_][0] = m;
      sMV[wv_][1] = rsqrtf(a2 * (1.f / 576.f) - m * m + 1e-5f);
    }
  }
  __syncthreads();

  const float m = sMV[pl][0], rs = sMV[pl][1];
  const size_t rowo = (size_t)b * 784 + pix;
  *(f32x4*)&x2[rowo * 576 + c] = (f32x4){y0, y1, y2v, y3};
  const f32x4 gv = *(const f32x4*)&g[c];
  const f32x4 bv = *(const f32x4*)&bet[c];
  ushort4 ob;
  __hip_bfloat16 h0 = __float2bfloat16((y0 - m) * rs * gv[0] + bv[0]); ob.x = *(ushort*)&h0;
  __hip_bfloat16 h1 = __float2bfloat16((y1 - m) * rs * gv[1] + bv[1]); ob.y = *(ushort*)&h1;
  __hip_bfloat16 h2 = __float2bfloat16((y2v - m) * rs * gv[2] + bv[2]); ob.z = *(ushort*)&h2;
  __hip_bfloat16 h3 = __float2bfloat16((y3 - m) * rs * gv[3] + bv[3]); ob.w = *(ushort*)&h3;
  *(ushort4*)&xn2[rowo * 576 + c] = ob;
}

// ---------- launch ----------
extern "C" void kernel_launch(void* const* d_in, const int* in_sizes, int n_in,
                              void* d_out, int out_size, void* d_ws, size_t ws_size,
                              hipStream_t stream) {
  (void)in_sizes; (void)n_in; (void)out_size; (void)ws_size;
  const float* x      = (const float*)d_in[0];
  const float* ln1g   = (const float*)d_in[1];
  const float* ln1b   = (const float*)d_in[2];
  const float* qkv_w  = (const float*)d_in[3];
  const float* qkv_b  = (const float*)d_in[4];
  const float* biases = (const float*)d_in[5];
  const float* proj_w = (const float*)d_in[6];
  const float* proj_b = (const float*)d_in[7];
  const float* conv_w = (const float*)d_in[8];
  const float* bng    = (const float*)d_in[9];
  const float* bnb    = (const float*)d_in[10];
  const float* bnm    = (const float*)d_in[11];
  const float* bnv    = (const float*)d_in[12];
  const float* ln2g   = (const float*)d_in[13];
  const float* ln2b   = (const float*)d_in[14];
  const float* fc1_w  = (const float*)d_in[15];
  const float* fc1_b  = (const float*)d_in[16];
  const float* fc2_w  = (const float*)d_in[17];
  const float* fc2_b  = (const float*)d_in[18];
  float* out = (float*)d_out;

  const int M = 25088;
  char* ws = (char*)d_ws;
  float* x2 = (float*)ws;
  char* regB = ws + 57802752;
  __hip_bfloat16* qkvb = (__hip_bfloat16*)regB;
  __hip_bfloat16* x1b  = (__hip_bfloat16*)regB;
  __hip_bfloat16* hm   = (__hip_bfloat16*)regB;
  char* regC = ws + 173408256;
  __hip_bfloat16* xn1  = (__hip_bfloat16*)regC;
  __hip_bfloat16* obuf = (__hip_bfloat16*)regC;
  __hip_bfloat16* xn2  = (__hip_bfloat16*)regC;
  char* regD = ws + 202309632;
  __hip_bfloat16* qkvT = (__hip_bfloat16*)regD;
  __hip_bfloat16* projT = (__hip_bfloat16*)(regD + 1990656);
  __hip_bfloat16* fc1T  = (__hip_bfloat16*)(regD + 1990656 + 663552);
  __hip_bfloat16* fc2T  = (__hip_bfloat16*)(regD + 1990656 + 663552 + 2654208);
  float* convT = (float*)(ws + 210272256);
  float* convST = convT + 9 * 576;

  // weight prep
  wt_kernel<<<dim3(1728 / 32, 576 / 32), 256, 0, stream>>>(qkv_w, qkvT, 576, 1728);
  wt_kernel<<<dim3(576 / 32, 576 / 32), 256, 0, stream>>>(proj_w, projT, 576, 576);
  wt_kernel<<<dim3(2304 / 32, 576 / 32), 256, 0, stream>>>(fc1_w, fc1T, 576, 2304);
  wt_kernel<<<dim3(576 / 32, 2304 / 32), 256, 0, stream>>>(fc2_w, fc2T, 2304, 576);
  convprep_kernel<<<(576 * 9 + 255) / 256, 256, 0, stream>>>(conv_w, bng, bnb, bnm, bnv, convT, convST);

  // 1. xn1 = LN1(x) bf16
  ln_bf16_kernel<<<M / 4, 256, 0, stream>>>(x, ln1g, ln1b, xn1);
  // 2. qkv = xn1 @ qkv_w + qkv_b (bf16 out); BN=96, grid 196 x 18
  gemm_bt<96, 0, __hip_bfloat16><<<196 * 18, 256, 0, stream>>>(xn1, qkvT, qkv_b, nullptr, qkvb, M, 1728, 576);
  // 3. attention (low-LDS MFMA)
  attn_mfma_kernel<<<512 * 18, 64, 0, stream>>>(qkvb, biases, obuf);
  // 4. x1 = x + (o @ proj_w + proj_b), stored bf16; BN=96, grid 196 x 6
  gemm_bt<96, 1, __hip_bfloat16><<<196 * 6, 256, 0, stream>>>(obuf, projT, proj_b, x, x1b, M, 576, 576);
  // 5+6. x2 = BN(dwconv(x1)); xn2 = LN2(x2)  (fused)
  conv_bn_ln_kernel<<<M / 4, 576, 0, stream>>>(x1b, convT, convST, ln2g, ln2b, x2, xn2);
  // 7. hm = gelu(xn2 @ fc1_w + fc1_b) bf16; BN=96, grid 196 x 24
  gemm_bt<96, 2, __hip_bfloat16><<<196 * 24, 256, 0, stream>>>(xn2, fc1T, fc1_b, nullptr, hm, M, 2304, 576);
  // 8. out = x2 + (hm @ fc2_w + fc2_b); BN=96, grid 196 x 6
  gemm_bt<96, 1, float><<<196 * 6, 256, 0, stream>>>(hm, fc2T, fc2_b, x2, out, M, 576, 2304);
}

// Round 24
// 462.806 us; speedup vs baseline: 1.9731x; 1.0299x over previous
//
#include <hip/hip_runtime.h>
#include <hip/hip_bf16.h>

typedef __attribute__((ext_vector_type(8))) short bf16x8;
typedef __attribute__((ext_vector_type(4))) float f32x4;

static __device__ __forceinline__ void stf(float* p, size_t i, float v) { p[i] = v; }
static __device__ __forceinline__ void stf(__hip_bfloat16* p, size_t i, float v) { p[i] = __float2bfloat16(v); }

static __device__ __forceinline__ void gload_lds16(const void* g, void* l) {
  __builtin_amdgcn_global_load_lds((const __attribute__((address_space(1))) void*)g,
                                   (__attribute__((address_space(3))) void*)l, 16, 0, 0);
}

// ---------- weight transpose + bf16 convert: W[K][N] f32 -> WT[N][K] bf16 ----------
__global__ void wt_kernel(const float* __restrict__ W, __hip_bfloat16* __restrict__ WT, int K, int N) {
  __shared__ float tile[32][33];
  const int kb = blockIdx.y * 32, nb = blockIdx.x * 32;
  const int tx = threadIdx.x & 31, ty = threadIdx.x >> 5;
#pragma unroll
  for (int i = 0; i < 4; ++i)
    tile[ty + i * 8][tx] = W[(size_t)(kb + ty + i * 8) * N + nb + tx];
  __syncthreads();
#pragma unroll
  for (int i = 0; i < 4; ++i)
    WT[(size_t)(nb + ty + i * 8) * K + kb + tx] = __float2bfloat16(tile[tx][ty + i * 8]);
}

// ---------- conv prep ----------
__global__ void convprep_kernel(const float* __restrict__ w, const float* __restrict__ bng,
                                const float* __restrict__ bnb, const float* __restrict__ bnm,
                                const float* __restrict__ bnv, float* __restrict__ wT,
                                float* __restrict__ st) {
  const int i = blockIdx.x * 256 + threadIdx.x;
  if (i < 576 * 9) {
    const int t = i / 576, c = i - t * 576;
    wT[i] = w[c * 9 + t];
  }
  if (i < 576) {
    const float s = rsqrtf(bnv[i] + 1e-5f) * bng[i];
    st[i] = s;
    st[576 + i] = bnb[i] - bnm[i] * s;
  }
}

// ---------- fused LN -> bf16 ----------
__global__ void ln_bf16_kernel(const float* __restrict__ x, const float* __restrict__ g,
                               const float* __restrict__ b, __hip_bfloat16* __restrict__ y) {
  const int row = blockIdx.x * 4 + (threadIdx.x >> 6);
  const int lane = threadIdx.x & 63;
  const float* p = x + (size_t)row * 576;
  float vals[9];
  float s = 0.f, ss = 0.f;
#pragma unroll
  for (int i = 0; i < 9; ++i) {
    float v = p[lane + i * 64];
    vals[i] = v; s += v; ss += v * v;
  }
#pragma unroll
  for (int o = 32; o; o >>= 1) { s += __shfl_down(s, o); ss += __shfl_down(ss, o); }
  s = __shfl(s, 0); ss = __shfl(ss, 0);
  const float m = s * (1.f / 576.f);
  const float rstd = rsqrtf(ss * (1.f / 576.f) - m * m + 1e-5f);
  __hip_bfloat16* q = y + (size_t)row * 576;
#pragma unroll
  for (int i = 0; i < 9; ++i) {
    const int c = lane + i * 64;
    q[c] = __float2bfloat16((vals[i] - m) * rstd * g[c] + b[c]);
  }
}

// ---------- MFMA GEMM (R16 structure, BN in {64,96}): 128xBN, BK=32 ----------
// BN=96: 28KB LDS, launch_bounds(256,5) -> 5 blk/CU (~62% occ) AND 61 F/B
// intensity (R23 fix: the (256,4) bound self-capped occupancy at 30%;
// measured VGPR=52 << 102-reg cap at 5 waves/EU -> spill-safe).
// BN=64: 24KB LDS, 6 blk/CU (R16-exact). Swizzle f(row)=(row>>1)&3
// both-sides; ascending-K accumulation (bit-identical across BN).
// EPI: 0 none, 1 +res, 2 exact GELU
template <int BN, int EPI, typename TO>
__global__ __launch_bounds__(256, (BN == 64 ? 6 : 5)) void gemm_bt(
    const __hip_bfloat16* __restrict__ A, const __hip_bfloat16* __restrict__ BT,
    const float* __restrict__ bias, const float* __restrict__ res, TO* __restrict__ C,
    int M, int N, int K) {
  constexpr int NI = BN / 32;          // frags per wave (wave tile 64 x BN/2)
  constexpr int BSLOTS = BN * 4;       // B stage slots (8 bf16 each)
  __shared__ __hip_bfloat16 sA[2][128 * 32];
  __shared__ __hip_bfloat16 sB[2][BN * 32];
  const int t = threadIdx.x;
  const int lane = t & 63;
  const int w = t >> 6;
  const int nwg = gridDim.x;
  const int qq = nwg >> 3, r = nwg & 7;
  const int xcd = blockIdx.x & 7, lidx = blockIdx.x >> 3;
  const int wgid = (xcd < r ? xcd * (qq + 1) : r * (qq + 1) + (xcd - r) * qq) + lidx;
  const int nx = N / BN;
  const int bm = (wgid / nx) * 128, bn = (wgid % nx) * BN;
  const int wm = (w >> 1) * 64, wn = (w & 1) * (BN / 2);
  const int l15 = lane & 15, l4 = lane >> 4;
  const int wave_base = t & ~63;

  f32x4 acc[4][NI];
#pragma unroll
  for (int mi = 0; mi < 4; ++mi)
#pragma unroll
    for (int ni = 0; ni < NI; ++ni) acc[mi][ni] = (f32x4){0.f, 0.f, 0.f, 0.f};

  auto stage = [&](int buf, int k0) {
#pragma unroll
    for (int i = 0; i < 2; ++i) {
      const int slot = i * 256 + t;
      const int row = slot >> 2, kst = slot & 3;
      const int ksrc = kst ^ ((row >> 1) & 3);
      gload_lds16(A + (size_t)(bm + row) * K + k0 + ksrc * 8,
                  sA[buf] + (i * 256 + wave_base) * 8);
    }
#pragma unroll
    for (int i = 0; i < (BSLOTS + 255) / 256; ++i) {
      const int slot = i * 256 + t;
      if (BSLOTS % 256 == 0 || slot < BSLOTS) {
        const int row = slot >> 2, kst = slot & 3;
        const int ksrc = kst ^ ((row >> 1) & 3);
        gload_lds16(BT + (size_t)(bn + row) * K + k0 + ksrc * 8,
                    sB[buf] + (i * 256 + wave_base) * 8);
      }
    }
  };

  auto compute = [&](int buf) {
    bf16x8 a[4], b[NI];
#pragma unroll
    for (int mi = 0; mi < 4; ++mi) {
      const int row = wm + mi * 16 + l15;
      a[mi] = *(const bf16x8*)(&sA[buf][row * 32 + ((l4 ^ ((row >> 1) & 3)) * 8)]);
    }
#pragma unroll
    for (int ni = 0; ni < NI; ++ni) {
      const int row = wn + ni * 16 + l15;
      b[ni] = *(const bf16x8*)(&sB[buf][row * 32 + ((l4 ^ ((row >> 1) & 3)) * 8)]);
    }
#pragma unroll
    for (int mi = 0; mi < 4; ++mi)
#pragma unroll
      for (int ni = 0; ni < NI; ++ni)
        acc[mi][ni] = __builtin_amdgcn_mfma_f32_16x16x32_bf16(a[mi], b[ni], acc[mi][ni], 0, 0, 0);
  };

  const int nt = K >> 5;
  stage(0, 0);
  __syncthreads();
  int cur = 0;
  for (int tt = 0; tt < nt - 1; ++tt) {
    stage(cur ^ 1, (tt + 1) << 5);
    compute(cur);
    __syncthreads();
    cur ^= 1;
  }
  compute(cur);

#pragma unroll
  for (int mi = 0; mi < 4; ++mi) {
    const int mrow = bm + wm + mi * 16 + l4 * 4;
#pragma unroll
    for (int ni = 0; ni < NI; ++ni) {
      const int col = bn + wn + ni * 16 + l15;
      const float bv = bias[col];
#pragma unroll
      for (int r2 = 0; r2 < 4; ++r2) {
        const size_t idx = (size_t)(mrow + r2) * N + col;
        float v = acc[mi][ni][r2] + bv;
        if (EPI == 1) v += res[idx];
        if (EPI == 2) v = 0.5f * v * (1.0f + erff(v * 0.70710678118654752f));
        stf(C, idx, v);
      }
    }
  }
}

// ---------- MFMA windowed attention, low-LDS (R12 config, kept) ----------
__global__ __launch_bounds__(64) void attn_mfma_kernel(
    const __hip_bfloat16* __restrict__ qkv, const float* __restrict__ biases,
    __hip_bfloat16* __restrict__ o) {
  __shared__ __hip_bfloat16 sVT[32][72];
  __shared__ __hip_bfloat16 sP[64][72];

  const int wid  = blockIdx.x / 18;
  const int head = blockIdx.x - wid * 18;
  const int b  = wid >> 4;
  const int wi = wid & 15;
  const int wh = wi >> 2, wwc = wi & 3;
  const int lane = threadIdx.x;
  const int l15 = lane & 15, l4 = lane >> 4;

  auto growof = [&](int tkn) -> size_t {
    const int r = tkn / 7, c = tkn - r * 7;
    return (size_t)b * 784 + (size_t)((wh * 7 + r) * 28 + wwc * 7 + c);
  };

  for (int idx = lane; idx < 49 * 4; idx += 64) {
    const int tkn = idx >> 2, part = idx & 3;
    const bf16x8 v = *(const bf16x8*)(qkv + growof(tkn) * 1728 + head * 96 + 64 + part * 8);
    const short* sv = (const short*)&v;
#pragma unroll
    for (int e = 0; e < 8; ++e)
      sVT[part * 8 + e][tkn] = *(const __hip_bfloat16*)&sv[e];
  }
  for (int idx = lane; idx < 32 * 15; idx += 64) {
    const int d = idx / 15, tt = 49 + (idx - d * 15);
    sVT[d][tt] = __float2bfloat16(0.0f);
  }

  bf16x8 aq[4], bk[4];
#pragma unroll
  for (int mi = 0; mi < 4; ++mi) {
    int tk = mi * 16 + l15; if (tk > 48) tk = 0;
    aq[mi] = *(const bf16x8*)(qkv + growof(tk) * 1728 + head * 96 + l4 * 8);
  }
#pragma unroll
  for (int ni = 0; ni < 4; ++ni) {
    int tk = ni * 16 + l15; if (tk > 48) tk = 0;
    bk[ni] = *(const bf16x8*)(qkv + growof(tk) * 1728 + head * 96 + 32 + l4 * 8);
  }

  f32x4 acc[4][4];
#pragma unroll
  for (int mi = 0; mi < 4; ++mi)
#pragma unroll
    for (int ni = 0; ni < 4; ++ni) acc[mi][ni] = (f32x4){0.f, 0.f, 0.f, 0.f};
#pragma unroll
  for (int mi = 0; mi < 4; ++mi)
#pragma unroll
    for (int ni = 0; ni < 4; ++ni)
      acc[mi][ni] = __builtin_amdgcn_mfma_f32_16x16x32_bf16(aq[mi], bk[ni], acc[mi][ni], 0, 0, 0);

  const float scale = 0.17677669529663687f;
  const float* btab = biases + head * 49;
#pragma unroll
  for (int mi = 0; mi < 4; ++mi) {
#pragma unroll
    for (int rr = 0; rr < 4; ++rr) {
      const int i = mi * 16 + l4 * 4 + rr;
      const int ic = i < 49 ? i : 0;
      const int ri = ic / 7, ci = ic - ri * 7;
      float s[4];
#pragma unroll
      for (int ni = 0; ni < 4; ++ni) {
        const int j = ni * 16 + l15;
        if (j < 49) {
          const int rj = j / 7, cj = j - rj * 7;
          s[ni] = acc[mi][ni][rr] * scale + btab[__builtin_abs(ri - rj) * 7 + __builtin_abs(ci - cj)];
        } else {
          s[ni] = -1e30f;
        }
      }
      float m = fmaxf(fmaxf(s[0], s[1]), fmaxf(s[2], s[3]));
#pragma unroll
      for (int d = 1; d < 16; d <<= 1) m = fmaxf(m, __shfl_xor(m, d));
      float sum = 0.f;
#pragma unroll
      for (int ni = 0; ni < 4; ++ni) { s[ni] = __expf(s[ni] - m); sum += s[ni]; }
#pragma unroll
      for (int d = 1; d < 16; d <<= 1) sum += __shfl_xor(sum, d);
      const float inv = 1.0f / sum;
#pragma unroll
      for (int ni = 0; ni < 4; ++ni)
        sP[i][ni * 16 + l15] = __float2bfloat16(s[ni] * inv);
    }
  }
  __syncthreads();

  f32x4 oacc[4][2];
#pragma unroll
  for (int mi = 0; mi < 4; ++mi)
#pragma unroll
    for (int ni = 0; ni < 2; ++ni) oacc[mi][ni] = (f32x4){0.f, 0.f, 0.f, 0.f};
#pragma unroll
  for (int kb = 0; kb < 2; ++kb) {
    bf16x8 ap[4], bv[2];
#pragma unroll
    for (int mi = 0; mi < 4; ++mi) ap[mi] = *(const bf16x8*)&sP[mi * 16 + l15][kb * 32 + l4 * 8];
#pragma unroll
    for (int ni = 0; ni < 2; ++ni) bv[ni] = *(const bf16x8*)&sVT[ni * 16 + l15][kb * 32 + l4 * 8];
#pragma unroll
    for (int mi = 0; mi < 4; ++mi)
#pragma unroll
      for (int ni = 0; ni < 2; ++ni)
        oacc[mi][ni] = __builtin_amdgcn_mfma_f32_16x16x32_bf16(ap[mi], bv[ni], oacc[mi][ni], 0, 0, 0);
  }

#pragma unroll
  for (int mi = 0; mi < 4; ++mi) {
#pragma unroll
    for (int rr = 0; rr < 4; ++rr) {
      const int i = mi * 16 + l4 * 4 + rr;
      if (i < 49) {
        const size_t grow = growof(i);
#pragma unroll
        for (int ni = 0; ni < 2; ++ni)
          o[grow * 576 + head * 32 + ni * 16 + l15] = __float2bfloat16(oacc[mi][ni][rr]);
      }
    }
  }
}

// ---------- fused depthwise conv3x3 + BN + LN2: x1(bf16) -> x2(f32) + xn2(bf16) ----------
__global__ __launch_bounds__(576) void conv_bn_ln_kernel(
    const __hip_bfloat16* __restrict__ x1b, const float* __restrict__ wT,
    const float* __restrict__ st, const float* __restrict__ g,
    const float* __restrict__ bet, float* __restrict__ x2,
    __hip_bfloat16* __restrict__ xn2) {
  __shared__ float sS[576], sSS[576];
  __shared__ float sMV[4][2];
  const int tid = threadIdx.x;
  const int pl = tid / 144, c4 = tid - pl * 144;
  const int p = blockIdx.x * 4 + pl;
  const int b = p / 784, pix = p - b * 784;
  const int i = pix / 28, j = pix - (pix / 28) * 28;
  const int c = c4 * 4;

  float y0 = 0.f, y1 = 0.f, y2v = 0.f, y3 = 0.f;
#pragma unroll
  for (int dh = -1; dh <= 1; ++dh) {
#pragma unroll
    for (int dw = -1; dw <= 1; ++dw) {
      const int ii = i + dh, jj = j + dw;
      if (ii >= 0 && ii < 28 && jj >= 0 && jj < 28) {
        const ushort4 u = *(const ushort4*)&x1b[((size_t)b * 784 + ii * 28 + jj) * 576 + c];
        const f32x4 wv = *(const f32x4*)&wT[((dh + 1) * 3 + (dw + 1)) * 576 + c];
        y0 += __bfloat162float(*(const __hip_bfloat16*)&u.x) * wv[0];
        y1 += __bfloat162float(*(const __hip_bfloat16*)&u.y) * wv[1];
        y2v += __bfloat162float(*(const __hip_bfloat16*)&u.z) * wv[2];
        y3 += __bfloat162float(*(const __hip_bfloat16*)&u.w) * wv[3];
      }
    }
  }
  const f32x4 sc = *(const f32x4*)&st[c];
  const f32x4 tt = *(const f32x4*)&st[576 + c];
  y0 = y0 * sc[0] + tt[0];
  y1 = y1 * sc[1] + tt[1];
  y2v = y2v * sc[2] + tt[2];
  y3 = y3 * sc[3] + tt[3];

  sS[tid] = y0 + y1 + y2v + y3;
  sSS[tid] = y0 * y0 + y1 * y1 + y2v * y2v + y3 * y3;
  __syncthreads();

  const int wv_ = tid >> 6, lane = tid & 63;
  if (wv_ < 4) {
    const int base = wv_ * 144;
    float a  = sS[base + lane] + sS[base + 64 + lane] + (lane < 16 ? sS[base + 128 + lane] : 0.f);
    float a2 = sSS[base + lane] + sSS[base + 64 + lane] + (lane < 16 ? sSS[base + 128 + lane] : 0.f);
#pragma unroll
    for (int o = 32; o; o >>= 1) { a += __shfl_down(a, o); a2 += __shfl_down(a2, o); }
    if (lane == 0) {
      const float m = a * (1.f / 576.f);
      sMV[wv_][0] = m;
      sMV[wv_][1] = rsqrtf(a2 * (1.f / 576.f) - m * m + 1e-5f);
    }
  }
  __syncthreads();

  const float m = sMV[pl][0], rs = sMV[pl][1];
  const size_t rowo = (size_t)b * 784 + pix;
  *(f32x4*)&x2[rowo * 576 + c] = (f32x4){y0, y1, y2v, y3};
  const f32x4 gv = *(const f32x4*)&g[c];
  const f32x4 bv = *(const f32x4*)&bet[c];
  ushort4 ob;
  __hip_bfloat16 h0 = __float2bfloat16((y0 - m) * rs * gv[0] + bv[0]); ob.x = *(ushort*)&h0;
  __hip_bfloat16 h1 = __float2bfloat16((y1 - m) * rs * gv[1] + bv[1]); ob.y = *(ushort*)&h1;
  __hip_bfloat16 h2 = __float2bfloat16((y2v - m) * rs * gv[2] + bv[2]); ob.z = *(ushort*)&h2;
  __hip_bfloat16 h3 = __float2bfloat16((y3 - m) * rs * gv[3] + bv[3]); ob.w = *(ushort*)&h3;
  *(ushort4*)&xn2[rowo * 576 + c] = ob;
}

// ---------- launch ----------
extern "C" void kernel_launch(void* const* d_in, const int* in_sizes, int n_in,
                              void* d_out, int out_size, void* d_ws, size_t ws_size,
                              hipStream_t stream) {
  (void)in_sizes; (void)n_in; (void)out_size; (void)ws_size;
  const float* x      = (const float*)d_in[0];
  const float* ln1g   = (const float*)d_in[1];
  const float* ln1b   = (const float*)d_in[2];
  const float* qkv_w  = (const float*)d_in[3];
  const float* qkv_b  = (const float*)d_in[4];
  const float* biases = (const float*)d_in[5];
  const float* proj_w = (const float*)d_in[6];
  const float* proj_b = (const float*)d_in[7];
  const float* conv_w = (const float*)d_in[8];
  const float* bng    = (const float*)d_in[9];
  const float* bnb    = (const float*)d_in[10];
  const float* bnm    = (const float*)d_in[11];
  const float* bnv    = (const float*)d_in[12];
  const float* ln2g   = (const float*)d_in[13];
  const float* ln2b   = (const float*)d_in[14];
  const float* fc1_w  = (const float*)d_in[15];
  const float* fc1_b  = (const float*)d_in[16];
  const float* fc2_w  = (const float*)d_in[17];
  const float* fc2_b  = (const float*)d_in[18];
  float* out = (float*)d_out;

  const int M = 25088;
  char* ws = (char*)d_ws;
  float* x2 = (float*)ws;
  char* regB = ws + 57802752;
  __hip_bfloat16* qkvb = (__hip_bfloat16*)regB;
  __hip_bfloat16* x1b  = (__hip_bfloat16*)regB;
  __hip_bfloat16* hm   = (__hip_bfloat16*)regB;
  char* regC = ws + 173408256;
  __hip_bfloat16* xn1  = (__hip_bfloat16*)regC;
  __hip_bfloat16* obuf = (__hip_bfloat16*)regC;
  __hip_bfloat16* xn2  = (__hip_bfloat16*)regC;
  char* regD = ws + 202309632;
  __hip_bfloat16* qkvT = (__hip_bfloat16*)regD;
  __hip_bfloat16* projT = (__hip_bfloat16*)(regD + 1990656);
  __hip_bfloat16* fc1T  = (__hip_bfloat16*)(regD + 1990656 + 663552);
  __hip_bfloat16* fc2T  = (__hip_bfloat16*)(regD + 1990656 + 663552 + 2654208);
  float* convT = (float*)(ws + 210272256);
  float* convST = convT + 9 * 576;

  // weight prep
  wt_kernel<<<dim3(1728 / 32, 576 / 32), 256, 0, stream>>>(qkv_w, qkvT, 576, 1728);
  wt_kernel<<<dim3(576 / 32, 576 / 32), 256, 0, stream>>>(proj_w, projT, 576, 576);
  wt_kernel<<<dim3(2304 / 32, 576 / 32), 256, 0, stream>>>(fc1_w, fc1T, 576, 2304);
  wt_kernel<<<dim3(576 / 32, 2304 / 32), 256, 0, stream>>>(fc2_w, fc2T, 2304, 576);
  convprep_kernel<<<(576 * 9 + 255) / 256, 256, 0, stream>>>(conv_w, bng, bnb, bnm, bnv, convT, convST);

  // 1. xn1 = LN1(x) bf16
  ln_bf16_kernel<<<M / 4, 256, 0, stream>>>(x, ln1g, ln1b, xn1);
  // 2. qkv = xn1 @ qkv_w + qkv_b (bf16 out); BN=96, grid 196 x 18
  gemm_bt<96, 0, __hip_bfloat16><<<196 * 18, 256, 0, stream>>>(xn1, qkvT, qkv_b, nullptr, qkvb, M, 1728, 576);
  // 3. attention (low-LDS MFMA)
  attn_mfma_kernel<<<512 * 18, 64, 0, stream>>>(qkvb, biases, obuf);
  // 4. x1 = x + (o @ proj_w + proj_b), stored bf16; BN=96, grid 196 x 6
  gemm_bt<96, 1, __hip_bfloat16><<<196 * 6, 256, 0, stream>>>(obuf, projT, proj_b, x, x1b, M, 576, 576);
  // 5+6. x2 = BN(dwconv(x1)); xn2 = LN2(x2)  (fused)
  conv_bn_ln_kernel<<<M / 4, 576, 0, stream>>>(x1b, convT, convST, ln2g, ln2b, x2, xn2);
  // 7. hm = gelu(xn2 @ fc1_w + fc1_b) bf16; BN=96, grid 196 x 24
  gemm_bt<96, 2, __hip_bfloat16><<<196 * 24, 256, 0, stream>>>(xn2, fc1T, fc1_b, nullptr, hm, M, 2304, 576);
  // 8. out = x2 + (hm @ fc2_w + fc2_b); BN=96, grid 196 x 6
  gemm_bt<96, 1, float><<<196 * 6, 256, 0, stream>>>(hm, fc2T, fc2_b, x2, out, M, 576, 2304);
}